// Round 6
// baseline (155.028 us; speedup 1.0000x reference)
//
#include <hip/hip_runtime.h>
#include <math.h>

// B=4, N=512, C=D=256, K=20, rows=2048
//
// ws layout (float offsets):
//   WtL [0, 65536)          W_l^T [c][d]
//   WtR [65536, 131072)
//   XL  [1048576, +524288)  [row][d] row-major
//   XRt [1572864, +524288)  [b][d][j] d-major
//   Av  [2097152, +2048)    dot(att, XL[row])
//   Bv  [2099200, +2048)    dot(att, XR[row])
//
// out (float): [0,40960) index_i | [40960,81920) index_j | [81920,122880) attention

// async global->LDS DMA, 16B per lane, lane l lands at lds_base + 16*l
#define GLD_LDS(gp, lp)                                                        \
    __builtin_amdgcn_global_load_lds(                                          \
        (const __attribute__((address_space(1))) float*)(gp),                  \
        (__attribute__((address_space(3))) float*)(lp), 16, 0, 0)

__global__ __launch_bounds__(256) void k_transpose(const float* __restrict__ Wl,
                                                   const float* __restrict__ Wr,
                                                   float* __restrict__ WtL,
                                                   float* __restrict__ WtR) {
    const int d = blockIdx.x, c = threadIdx.x;  // coalesced read of W[d][:]
    if (blockIdx.y == 0) WtL[c * 256 + d] = Wl[d * 256 + c];
    else                 WtR[c * 256 + d] = Wr[d * 256 + c];
}

// 256 wgs x 512 thr; wg = 8 rows. thread = (dq = tid&63 -> d-quad, rq = bit6 ->
// 4 rows, ch = tid>>7 -> 64-c range). W read as coalesced b128 from L2 (1 KB/inst,
// 8 in flight per unrolled iter). x transposed in LDS -> 1 uniform b128 per c.
__global__ __launch_bounds__(512, 4) void k_proj(const float* __restrict__ x,
        const float* __restrict__ WtL, const float* __restrict__ WtR,
        const float* __restrict__ bl, const float* __restrict__ br,
        const float* __restrict__ att,
        float* __restrict__ XL, float* __restrict__ XRt,
        float* __restrict__ Av, float* __restrict__ Bv) {
    __shared__ __align__(16) float xst[256 * 12];   // x[c][r] at c*12+r (48B stride: b128-aligned)
    __shared__ __align__(16) float mrg[3 * 4096];   // ch=1..3 partials [(r8*2+s)*256 + d]
    const int tid = threadIdx.x;
    const int dq = tid & 63;
    const int rq = (tid >> 6) & 1;
    const int ch = tid >> 7;           // 0..3 (wave-pair uniform)
    const int R = blockIdx.x * 8;
    const int b = R >> 9, jr0 = R & 511;

    // stage x transposed: thread reads one float4 of x, scatters 4 c-slots
    {
        const float4 xv = ((const float4*)(x + (size_t)R * 256))[tid];
        const int r = tid >> 6;        // 0..7
        const int c4 = (tid & 63) * 4;
        xst[(c4 + 0) * 12 + r] = xv.x;
        xst[(c4 + 1) * 12 + r] = xv.y;
        xst[(c4 + 2) * 12 + r] = xv.z;
        xst[(c4 + 3) * 12 + r] = xv.w;
    }
    __syncthreads();

    float aL[4][4], aR[4][4];          // [r][dcomp]
#pragma unroll
    for (int r = 0; r < 4; ++r)
#pragma unroll
        for (int k = 0; k < 4; ++k) { aL[r][k] = 0.f; aR[r][k] = 0.f; }

    const int c0 = ch * 64;
    const float* WLp = WtL + (size_t)c0 * 256 + dq * 4;
    const float* WRp = WtR + (size_t)c0 * 256 + dq * 4;
#pragma unroll 4
    for (int cc = 0; cc < 64; ++cc) {
        const float4 wl = *(const float4*)(WLp + (size_t)cc * 256);   // coalesced 1 KB/wave
        const float4 wr = *(const float4*)(WRp + (size_t)cc * 256);
        const float4 xv = *(const float4*)&xst[(c0 + cc) * 12 + rq * 4]; // uniform b128: 4 rows
#define PROJ_R(r, XS)                                  \
        aL[r][0] = fmaf(XS, wl.x, aL[r][0]);           \
        aL[r][1] = fmaf(XS, wl.y, aL[r][1]);           \
        aL[r][2] = fmaf(XS, wl.z, aL[r][2]);           \
        aL[r][3] = fmaf(XS, wl.w, aL[r][3]);           \
        aR[r][0] = fmaf(XS, wr.x, aR[r][0]);           \
        aR[r][1] = fmaf(XS, wr.y, aR[r][1]);           \
        aR[r][2] = fmaf(XS, wr.z, aR[r][2]);           \
        aR[r][3] = fmaf(XS, wr.w, aR[r][3]);
        PROJ_R(0, xv.x)
        PROJ_R(1, xv.y)
        PROJ_R(2, xv.z)
        PROJ_R(3, xv.w)
#undef PROJ_R
    }

    if (ch > 0) {
        float* m = &mrg[(ch - 1) * 4096];
#pragma unroll
        for (int r = 0; r < 4; ++r) {
            const int r8 = rq * 4 + r;
            *(float4*)&m[(r8 * 2 + 0) * 256 + dq * 4] = make_float4(aL[r][0], aL[r][1], aL[r][2], aL[r][3]);
            *(float4*)&m[(r8 * 2 + 1) * 256 + dq * 4] = make_float4(aR[r][0], aR[r][1], aR[r][2], aR[r][3]);
        }
    }
    __syncthreads();

    if (ch == 0) {
        const float4 bl4 = *(const float4*)&bl[dq * 4];
        const float4 br4 = *(const float4*)&br[dq * 4];
        const float4 at4 = *(const float4*)&att[dq * 4];
        float pa[4], pb[4];
#pragma unroll
        for (int r = 0; r < 4; ++r) {
            const int r8 = rq * 4 + r;
            const float4 mL0 = *(const float4*)&mrg[(r8 * 2 + 0) * 256 + dq * 4];
            const float4 mL1 = *(const float4*)&mrg[4096 + (r8 * 2 + 0) * 256 + dq * 4];
            const float4 mL2 = *(const float4*)&mrg[8192 + (r8 * 2 + 0) * 256 + dq * 4];
            const float4 mR0 = *(const float4*)&mrg[(r8 * 2 + 1) * 256 + dq * 4];
            const float4 mR1 = *(const float4*)&mrg[4096 + (r8 * 2 + 1) * 256 + dq * 4];
            const float4 mR2 = *(const float4*)&mrg[8192 + (r8 * 2 + 1) * 256 + dq * 4];
            float4 sl, sr;
            sl.x = aL[r][0] + mL0.x + mL1.x + mL2.x + bl4.x;
            sl.y = aL[r][1] + mL0.y + mL1.y + mL2.y + bl4.y;
            sl.z = aL[r][2] + mL0.z + mL1.z + mL2.z + bl4.z;
            sl.w = aL[r][3] + mL0.w + mL1.w + mL2.w + bl4.w;
            sr.x = aR[r][0] + mR0.x + mR1.x + mR2.x + br4.x;
            sr.y = aR[r][1] + mR0.y + mR1.y + mR2.y + br4.y;
            sr.z = aR[r][2] + mR0.z + mR1.z + mR2.z + br4.z;
            sr.w = aR[r][3] + mR0.w + mR1.w + mR2.w + br4.w;
            *(float4*)&XL[(size_t)(R + r8) * 256 + dq * 4] = sl;   // coalesced
            const size_t xrb0 = ((size_t)(b * 256 + dq * 4)) * 512 + jr0 + r8;
            XRt[xrb0 + 0 * 512] = sr.x;                            // scattered (2 MB total, L2)
            XRt[xrb0 + 1 * 512] = sr.y;
            XRt[xrb0 + 2 * 512] = sr.z;
            XRt[xrb0 + 3 * 512] = sr.w;
            pa[r] = at4.x * sl.x + at4.y * sl.y + at4.z * sl.z + at4.w * sl.w;
            pb[r] = at4.x * sr.x + at4.y * sr.y + at4.z * sr.z + at4.w * sr.w;
        }
#pragma unroll
        for (int r = 0; r < 4; ++r) {
#pragma unroll
            for (int off = 32; off; off >>= 1) {
                pa[r] += __shfl_xor(pa[r], off);
                pb[r] += __shfl_xor(pb[r], off);
            }
        }
        if (dq == 0) {                 // lane 0 of each rq-wave
#pragma unroll
            for (int r = 0; r < 4; ++r) {
                Av[R + rq * 4 + r] = pa[r];
                Bv[R + rq * 4 + r] = pb[r];
            }
        }
    }
}

// Fused pair + top-k + softmax. 512 wgs x 128 thr; wg = 4 rows x all 512 j.
// Thread owns a j-quad (j = tid*4..+3) for all 4 rows: 16 accs, no d-split.
// XRt staged by global_load_lds DMA, double-buffered, 1 barrier/chunk.
__global__ __launch_bounds__(128) void k_pair_topk(const float* __restrict__ XL,
        const float* __restrict__ XRt, const float* __restrict__ Av,
        const float* __restrict__ Bv, const float* __restrict__ att,
        float* __restrict__ out) {
    __shared__ __align__(16) float xrb[2][8 * 512];  // 32 KB staging
    __shared__ __align__(16) float xls[4 * 256];
    __shared__ __align__(16) float atts[256];
    __shared__ __align__(16) float alph[4 * 512];
    const int tid = threadIdx.x;     // 0..127
    const int lane = tid & 63;
    const int w = tid >> 6;          // wave 0..1
    const int g = blockIdx.x;        // 0..511
    const int R = g * 4, b = R >> 9;
    const float* __restrict__ XRb = XRt + (size_t)b * 256 * 512;

    // stage chunk 0: wave w DMAs dd-rows 4w..4w+3 (each row 512 floats = 2 insts)
    {
        const float* gr = XRb + (size_t)(4 * w) * 512;
        float* lr = &xrb[0][(4 * w) * 512];
#pragma unroll
        for (int rr = 0; rr < 4; ++rr) {
            GLD_LDS(gr + rr * 512 + lane * 4, lr + rr * 512);
            GLD_LDS(gr + rr * 512 + 256 + lane * 4, lr + rr * 512 + 256);
        }
    }
    // stage xls (1024 floats) + atts (256)
    ((float4*)xls)[tid] = ((const float4*)(XL + (size_t)R * 256))[tid];
    ((float4*)xls)[tid + 128] = ((const float4*)(XL + (size_t)R * 256))[tid + 128];
    if (tid < 64) ((float4*)atts)[tid] = ((const float4*)att)[tid];

    float acc[4][4];
#pragma unroll
    for (int i = 0; i < 4; ++i)
#pragma unroll
        for (int jj = 0; jj < 4; ++jj) acc[i][jj] = 0.f;

    for (int ch = 0; ch < 32; ++ch) {
        __syncthreads();               // buf[ch&1] ready (DMA had full prior chunk to fly)
        const int bf = ch & 1;
        if (ch < 31) {                 // issue next-chunk DMA before computing
            const float* gr = XRb + (size_t)((ch + 1) * 8 + 4 * w) * 512;
            float* lr = &xrb[bf ^ 1][(4 * w) * 512];
#pragma unroll
            for (int rr = 0; rr < 4; ++rr) {
                GLD_LDS(gr + rr * 512 + lane * 4, lr + rr * 512);
                GLD_LDS(gr + rr * 512 + 256 + lane * 4, lr + rr * 512 + 256);
            }
        }
        const int d0 = ch * 8;
        // hoist xl/att for this chunk into registers (b128 broadcasts)
        float ats[8], xli[4][8];
        {
            const float4 a0 = *(const float4*)&atts[d0];
            const float4 a1 = *(const float4*)&atts[d0 + 4];
            ats[0] = a0.x; ats[1] = a0.y; ats[2] = a0.z; ats[3] = a0.w;
            ats[4] = a1.x; ats[5] = a1.y; ats[6] = a1.z; ats[7] = a1.w;
#pragma unroll
            for (int i = 0; i < 4; ++i) {
                const float4 x0 = *(const float4*)&xls[i * 256 + d0];
                const float4 x1 = *(const float4*)&xls[i * 256 + d0 + 4];
                xli[i][0] = x0.x; xli[i][1] = x0.y; xli[i][2] = x0.z; xli[i][3] = x0.w;
                xli[i][4] = x1.x; xli[i][5] = x1.y; xli[i][6] = x1.z; xli[i][7] = x1.w;
            }
        }
#pragma unroll
        for (int dd = 0; dd < 8; ++dd) {
            const float4 xr = *(const float4*)&xrb[bf][dd * 512 + tid * 4];  // conflict-free
            const float ad = ats[dd];
#pragma unroll
            for (int i = 0; i < 4; ++i) {
                const float xl = xli[i][dd];
                acc[i][0] = fmaf(ad, fabsf(xl + xr.x), acc[i][0]);  // abs = free modifier
                acc[i][1] = fmaf(ad, fabsf(xl + xr.y), acc[i][1]);
                acc[i][2] = fmaf(ad, fabsf(xl + xr.z), acc[i][2]);
                acc[i][3] = fmaf(ad, fabsf(xl + xr.w), acc[i][3]);
            }
        }
    }

    // finish alpha (no merge needed: thread owns full d-reduction)
    {
        const float4 Bj = *(const float4*)&Bv[b * 512 + tid * 4];
#pragma unroll
        for (int i = 0; i < 4; ++i) {
            const float Ai = Av[R + i];
            float a0 = fmaf(0.4f, acc[i][0], 0.6f * (Ai + Bj.x));
            float a1 = fmaf(0.4f, acc[i][1], 0.6f * (Ai + Bj.y));
            float a2 = fmaf(0.4f, acc[i][2], 0.6f * (Ai + Bj.z));
            float a3 = fmaf(0.4f, acc[i][3], 0.6f * (Ai + Bj.w));
            if (!isfinite(a0)) a0 = 0.f;   // nan_to_num
            if (!isfinite(a1)) a1 = 0.f;
            if (!isfinite(a2)) a2 = 0.f;
            if (!isfinite(a3)) a3 = 0.f;
            *(float4*)&alph[i * 512 + tid * 4] = make_float4(a0, a1, a2, a3);
        }
    }
    __syncthreads();

    // top-20 + softmax: wave w handles rows 2w, 2w+1
    for (int ri = 0; ri < 2; ++ri) {
        const int i = 2 * w + ri;
        const float* ar = &alph[i * 512];
        const float4 u0 = *(const float4*)&ar[lane * 8];
        const float4 u1 = *(const float4*)&ar[lane * 8 + 4];
        float v[8] = {u0.x, u0.y, u0.z, u0.w, u1.x, u1.y, u1.z, u1.w};  // j = lane*8+t

        float myval = 0.f, mmax = 0.f;
        int myidx = 0;
        for (int sel = 0; sel < 20; ++sel) {
            float bv = v[0]; int bt = 0;
#pragma unroll
            for (int t = 1; t < 8; ++t) { if (v[t] > bv) { bv = v[t]; bt = t; } }
            int bj = lane * 8 + bt;
#pragma unroll
            for (int off = 32; off; off >>= 1) {   // butterfly argmax, lower j wins ties
                const float ov = __shfl_xor(bv, off);
                const int   oj = __shfl_xor(bj, off);
                if (ov > bv || (ov == bv && oj < bj)) { bv = ov; bj = oj; }
            }
            if (sel == 0) mmax = bv;
            if (lane == sel) { myval = bv; myidx = bj; }
            if ((bj >> 3) == lane) {
                const int bt2 = bj & 7;
#pragma unroll
                for (int t = 0; t < 8; ++t) if (t == bt2) v[t] = -INFINITY;
            }
        }
        const float e = (lane < 20) ? expf(myval - mmax) : 0.f;
        float s = e;
#pragma unroll
        for (int off = 32; off; off >>= 1) s += __shfl_xor(s, off);
        if (lane < 20) {
            const int row = R + i;
            const int base = row * 20 + lane;
            out[base] = (float)row;                        // index_i
            out[40960 + base] = (float)(b * 512 + myidx);  // index_j
            out[81920 + base] = e / s;                     // attention
        }
    }
}

extern "C" void kernel_launch(void* const* d_in, const int* in_sizes, int n_in,
                              void* d_out, int out_size, void* d_ws, size_t ws_size,
                              hipStream_t stream) {
    const float* x   = (const float*)d_in[0];
    const float* Wl  = (const float*)d_in[3];
    const float* bl  = (const float*)d_in[4];
    const float* Wr  = (const float*)d_in[5];
    const float* br  = (const float*)d_in[6];
    const float* att = (const float*)d_in[7];

    float* ws  = (float*)d_ws;
    float* WtL = ws;
    float* WtR = ws + 65536;
    float* XL  = ws + 1048576;
    float* XRt = ws + 1572864;
    float* Av  = ws + 2097152;
    float* Bv  = ws + 2099200;
    float* out = (float*)d_out;

    k_transpose<<<dim3(256, 2), dim3(256), 0, stream>>>(Wl, Wr, WtL, WtR);
    k_proj<<<dim3(256), dim3(512), 0, stream>>>(x, WtL, WtR, bl, br, att, XL, XRt, Av, Bv);
    k_pair_topk<<<dim3(512), dim3(128), 0, stream>>>(XL, XRt, Av, Bv, att, out);
}

// Round 7
// 117.163 us; speedup vs baseline: 1.3232x; 1.3232x over previous
//
#include <hip/hip_runtime.h>
#include <math.h>

// B=4, N=512, C=D=256, K=20, rows=2048
//
// ws layout (float offsets):
//   WtL [0, 65536)          W_l^T [c][d]
//   WtR [65536, 131072)
//   XL  [1048576, +524288)  [row][d] row-major
//   XRt [1572864, +524288)  [b][d][j] d-major
//   Av  [2097152, +2048)    dot(att, XL[row])
//   Bv  [2099200, +2048)    dot(att, XR[row])
//
// out (float): [0,40960) index_i | [40960,81920) index_j | [81920,122880) attention

__global__ __launch_bounds__(256) void k_transpose(const float* __restrict__ Wl,
                                                   const float* __restrict__ Wr,
                                                   float* __restrict__ WtL,
                                                   float* __restrict__ WtR) {
    const int d = blockIdx.x, c = threadIdx.x;  // coalesced read of W[d][:]
    if (blockIdx.y == 0) WtL[c * 256 + d] = Wl[d * 256 + c];
    else                 WtR[c * 256 + d] = Wr[d * 256 + c];
}

// 256 wgs x 512 thr; wg = 8 rows. (unchanged from R6)
__global__ __launch_bounds__(512, 4) void k_proj(const float* __restrict__ x,
        const float* __restrict__ WtL, const float* __restrict__ WtR,
        const float* __restrict__ bl, const float* __restrict__ br,
        const float* __restrict__ att,
        float* __restrict__ XL, float* __restrict__ XRt,
        float* __restrict__ Av, float* __restrict__ Bv) {
    __shared__ __align__(16) float xst[256 * 12];   // x[c][r] at c*12+r
    __shared__ __align__(16) float mrg[3 * 4096];
    const int tid = threadIdx.x;
    const int dq = tid & 63;
    const int rq = (tid >> 6) & 1;
    const int ch = tid >> 7;           // 0..3
    const int R = blockIdx.x * 8;
    const int b = R >> 9, jr0 = R & 511;

    {
        const float4 xv = ((const float4*)(x + (size_t)R * 256))[tid];
        const int r = tid >> 6;
        const int c4 = (tid & 63) * 4;
        xst[(c4 + 0) * 12 + r] = xv.x;
        xst[(c4 + 1) * 12 + r] = xv.y;
        xst[(c4 + 2) * 12 + r] = xv.z;
        xst[(c4 + 3) * 12 + r] = xv.w;
    }
    __syncthreads();

    float aL[4][4], aR[4][4];
#pragma unroll
    for (int r = 0; r < 4; ++r)
#pragma unroll
        for (int k = 0; k < 4; ++k) { aL[r][k] = 0.f; aR[r][k] = 0.f; }

    const int c0 = ch * 64;
    const float* WLp = WtL + (size_t)c0 * 256 + dq * 4;
    const float* WRp = WtR + (size_t)c0 * 256 + dq * 4;
#pragma unroll 4
    for (int cc = 0; cc < 64; ++cc) {
        const float4 wl = *(const float4*)(WLp + (size_t)cc * 256);
        const float4 wr = *(const float4*)(WRp + (size_t)cc * 256);
        const float4 xv = *(const float4*)&xst[(c0 + cc) * 12 + rq * 4];
#define PROJ_R(r, XS)                                  \
        aL[r][0] = fmaf(XS, wl.x, aL[r][0]);           \
        aL[r][1] = fmaf(XS, wl.y, aL[r][1]);           \
        aL[r][2] = fmaf(XS, wl.z, aL[r][2]);           \
        aL[r][3] = fmaf(XS, wl.w, aL[r][3]);           \
        aR[r][0] = fmaf(XS, wr.x, aR[r][0]);           \
        aR[r][1] = fmaf(XS, wr.y, aR[r][1]);           \
        aR[r][2] = fmaf(XS, wr.z, aR[r][2]);           \
        aR[r][3] = fmaf(XS, wr.w, aR[r][3]);
        PROJ_R(0, xv.x)
        PROJ_R(1, xv.y)
        PROJ_R(2, xv.z)
        PROJ_R(3, xv.w)
#undef PROJ_R
    }

    if (ch > 0) {
        float* m = &mrg[(ch - 1) * 4096];
#pragma unroll
        for (int r = 0; r < 4; ++r) {
            const int r8 = rq * 4 + r;
            *(float4*)&m[(r8 * 2 + 0) * 256 + dq * 4] = make_float4(aL[r][0], aL[r][1], aL[r][2], aL[r][3]);
            *(float4*)&m[(r8 * 2 + 1) * 256 + dq * 4] = make_float4(aR[r][0], aR[r][1], aR[r][2], aR[r][3]);
        }
    }
    __syncthreads();

    if (ch == 0) {
        const float4 bl4 = *(const float4*)&bl[dq * 4];
        const float4 br4 = *(const float4*)&br[dq * 4];
        const float4 at4 = *(const float4*)&att[dq * 4];
        float pa[4], pb[4];
#pragma unroll
        for (int r = 0; r < 4; ++r) {
            const int r8 = rq * 4 + r;
            const float4 mL0 = *(const float4*)&mrg[(r8 * 2 + 0) * 256 + dq * 4];
            const float4 mL1 = *(const float4*)&mrg[4096 + (r8 * 2 + 0) * 256 + dq * 4];
            const float4 mL2 = *(const float4*)&mrg[8192 + (r8 * 2 + 0) * 256 + dq * 4];
            const float4 mR0 = *(const float4*)&mrg[(r8 * 2 + 1) * 256 + dq * 4];
            const float4 mR1 = *(const float4*)&mrg[4096 + (r8 * 2 + 1) * 256 + dq * 4];
            const float4 mR2 = *(const float4*)&mrg[8192 + (r8 * 2 + 1) * 256 + dq * 4];
            float4 sl, sr;
            sl.x = aL[r][0] + mL0.x + mL1.x + mL2.x + bl4.x;
            sl.y = aL[r][1] + mL0.y + mL1.y + mL2.y + bl4.y;
            sl.z = aL[r][2] + mL0.z + mL1.z + mL2.z + bl4.z;
            sl.w = aL[r][3] + mL0.w + mL1.w + mL2.w + bl4.w;
            sr.x = aR[r][0] + mR0.x + mR1.x + mR2.x + br4.x;
            sr.y = aR[r][1] + mR0.y + mR1.y + mR2.y + br4.y;
            sr.z = aR[r][2] + mR0.z + mR1.z + mR2.z + br4.z;
            sr.w = aR[r][3] + mR0.w + mR1.w + mR2.w + br4.w;
            *(float4*)&XL[(size_t)(R + r8) * 256 + dq * 4] = sl;
            const size_t xrb0 = ((size_t)(b * 256 + dq * 4)) * 512 + jr0 + r8;
            XRt[xrb0 + 0 * 512] = sr.x;
            XRt[xrb0 + 1 * 512] = sr.y;
            XRt[xrb0 + 2 * 512] = sr.z;
            XRt[xrb0 + 3 * 512] = sr.w;
            pa[r] = at4.x * sl.x + at4.y * sl.y + at4.z * sl.z + at4.w * sl.w;
            pb[r] = at4.x * sr.x + at4.y * sr.y + at4.z * sr.z + at4.w * sr.w;
        }
#pragma unroll
        for (int r = 0; r < 4; ++r) {
#pragma unroll
            for (int off = 32; off; off >>= 1) {
                pa[r] += __shfl_xor(pa[r], off);
                pb[r] += __shfl_xor(pb[r], off);
            }
        }
        if (dq == 0) {
#pragma unroll
            for (int r = 0; r < 4; ++r) {
                Av[R + rq * 4 + r] = pa[r];
                Bv[R + rq * 4 + r] = pb[r];
            }
        }
    }
}

// Fused pair + top-k + softmax. 256 wgs x 512 thr; wg = 8 rows x all 512 j.
// Thread: jc = tid&127 -> j-quad, h = tid>>7 -> d-quarter (64 d), ALL 8 i.
// 8-i reuse per xr float4 load => 512 vmem wave-insts/CU (was 2048).
// Register-double-buffered prefetch; (512,2) bounds give 256-VGPR headroom.
__global__ __launch_bounds__(512, 2) void k_pair_topk(const float* __restrict__ XL,
        const float* __restrict__ XRt, const float* __restrict__ Av,
        const float* __restrict__ Bv, const float* __restrict__ att,
        float* __restrict__ out) {
    __shared__ __align__(16) float xls[8 * 256];     // 8 KB
    __shared__ __align__(16) float atts[256];        // 1 KB
    __shared__ __align__(16) float mrg[3 * 4096];    // 48 KB: h=1..3 partials [i][j]
    __shared__ __align__(16) float alph[8 * 512];    // 16 KB
    const int tid = threadIdx.x;       // 0..511
    const int jc = tid & 127;          // j-quad index
    const int h = tid >> 7;            // d-quarter 0..3 (wave-uniform)
    const int g = blockIdx.x;          // 0..255
    const int R = g * 8, b = R >> 9;

    // stage xl rows + att
    ((float4*)xls)[tid] = ((const float4*)(XL + (size_t)R * 256))[tid];
    if (tid < 64) ((float4*)atts)[tid] = ((const float4*)att)[tid];
    __syncthreads();

    const int dbase = h * 64;
    const float* __restrict__ xrp = XRt + (size_t)b * 131072 + (size_t)dbase * 512 + jc * 4;

    float acc[8][4];
#pragma unroll
    for (int i = 0; i < 8; ++i)
#pragma unroll
        for (int c = 0; c < 4; ++c) acc[i][c] = 0.f;

    float4 bufA[8], bufB[8];
#pragma unroll
    for (int dd = 0; dd < 8; ++dd) bufA[dd] = *(const float4*)(xrp + (size_t)dd * 512);

#pragma unroll
    for (int ch = 0; ch < 8; ++ch) {
        const float4* cur = (ch & 1) ? bufB : bufA;   // static under full unroll
        float4* nxt = (ch & 1) ? bufA : bufB;
        if (ch < 7) {
            const float* p = xrp + (size_t)(ch + 1) * 8 * 512;
#pragma unroll
            for (int dd = 0; dd < 8; ++dd) nxt[dd] = *(const float4*)(p + (size_t)dd * 512);
        }
        const int d0 = dbase + ch * 8;
        const float4 at0 = *(const float4*)&atts[d0];      // LDS b128 broadcast
        const float4 at1 = *(const float4*)&atts[d0 + 4];
#pragma unroll
        for (int i = 0; i < 8; ++i) {
            const float4 xa = *(const float4*)&xls[i * 256 + d0];
            const float4 xb = *(const float4*)&xls[i * 256 + d0 + 4];
#define PSTEP(XLC, ATC, XR4)                                       \
            acc[i][0] = fmaf(ATC, fabsf(XLC + XR4.x), acc[i][0]);   \
            acc[i][1] = fmaf(ATC, fabsf(XLC + XR4.y), acc[i][1]);   \
            acc[i][2] = fmaf(ATC, fabsf(XLC + XR4.z), acc[i][2]);   \
            acc[i][3] = fmaf(ATC, fabsf(XLC + XR4.w), acc[i][3]);
            PSTEP(xa.x, at0.x, cur[0])
            PSTEP(xa.y, at0.y, cur[1])
            PSTEP(xa.z, at0.z, cur[2])
            PSTEP(xa.w, at0.w, cur[3])
            PSTEP(xb.x, at1.x, cur[4])
            PSTEP(xb.y, at1.y, cur[5])
            PSTEP(xb.z, at1.z, cur[6])
            PSTEP(xb.w, at1.w, cur[7])
#undef PSTEP
        }
    }

    // merge d-quarters: h=1..3 dump partials, h=0 finishes
    if (h) {
        float* m = &mrg[(h - 1) * 4096];
#pragma unroll
        for (int i = 0; i < 8; ++i)
            *(float4*)&m[i * 512 + jc * 4] = make_float4(acc[i][0], acc[i][1], acc[i][2], acc[i][3]);
    }
    __syncthreads();
    if (h == 0) {
        const float4 Bj = *(const float4*)&Bv[b * 512 + jc * 4];
#pragma unroll
        for (int i = 0; i < 8; ++i) {
            const float Ai = Av[R + i];
            const float4 m0 = *(const float4*)&mrg[i * 512 + jc * 4];
            const float4 m1 = *(const float4*)&mrg[4096 + i * 512 + jc * 4];
            const float4 m2 = *(const float4*)&mrg[8192 + i * 512 + jc * 4];
            float a0 = fmaf(0.4f, acc[i][0] + m0.x + m1.x + m2.x, 0.6f * (Ai + Bj.x));
            float a1 = fmaf(0.4f, acc[i][1] + m0.y + m1.y + m2.y, 0.6f * (Ai + Bj.y));
            float a2 = fmaf(0.4f, acc[i][2] + m0.z + m1.z + m2.z, 0.6f * (Ai + Bj.z));
            float a3 = fmaf(0.4f, acc[i][3] + m0.w + m1.w + m2.w, 0.6f * (Ai + Bj.w));
            if (!isfinite(a0)) a0 = 0.f;   // nan_to_num
            if (!isfinite(a1)) a1 = 0.f;
            if (!isfinite(a2)) a2 = 0.f;
            if (!isfinite(a3)) a3 = 0.f;
            *(float4*)&alph[i * 512 + jc * 4] = make_float4(a0, a1, a2, a3);
        }
    }
    __syncthreads();

    // top-20 + softmax: wave w handles row w (8 waves, 8 rows)
    const int lane = tid & 63;
    const int i = tid >> 6;
    const float* ar = &alph[i * 512];
    const float4 u0 = *(const float4*)&ar[lane * 8];
    const float4 u1 = *(const float4*)&ar[lane * 8 + 4];
    float v[8] = {u0.x, u0.y, u0.z, u0.w, u1.x, u1.y, u1.z, u1.w};  // j = lane*8+t

    float myval = 0.f, mmax = 0.f;
    int myidx = 0;
    for (int sel = 0; sel < 20; ++sel) {
        float bv = v[0]; int bt = 0;
#pragma unroll
        for (int t = 1; t < 8; ++t) { if (v[t] > bv) { bv = v[t]; bt = t; } }
        int bj = lane * 8 + bt;
#pragma unroll
        for (int off = 32; off; off >>= 1) {   // butterfly argmax, lower j wins ties
            const float ov = __shfl_xor(bv, off);
            const int   oj = __shfl_xor(bj, off);
            if (ov > bv || (ov == bv && oj < bj)) { bv = ov; bj = oj; }
        }
        if (sel == 0) mmax = bv;
        if (lane == sel) { myval = bv; myidx = bj; }
        if ((bj >> 3) == lane) {
            const int bt2 = bj & 7;
#pragma unroll
            for (int t = 0; t < 8; ++t) if (t == bt2) v[t] = -INFINITY;
        }
    }
    const float e = (lane < 20) ? expf(myval - mmax) : 0.f;
    float s = e;
#pragma unroll
    for (int off = 32; off; off >>= 1) s += __shfl_xor(s, off);
    if (lane < 20) {
        const int row = R + i;
        const int base = row * 20 + lane;
        out[base] = (float)row;                        // index_i
        out[40960 + base] = (float)(b * 512 + myidx);  // index_j
        out[81920 + base] = e / s;                     // attention
    }
}

extern "C" void kernel_launch(void* const* d_in, const int* in_sizes, int n_in,
                              void* d_out, int out_size, void* d_ws, size_t ws_size,
                              hipStream_t stream) {
    const float* x   = (const float*)d_in[0];
    const float* Wl  = (const float*)d_in[3];
    const float* bl  = (const float*)d_in[4];
    const float* Wr  = (const float*)d_in[5];
    const float* br  = (const float*)d_in[6];
    const float* att = (const float*)d_in[7];

    float* ws  = (float*)d_ws;
    float* WtL = ws;
    float* WtR = ws + 65536;
    float* XL  = ws + 1048576;
    float* XRt = ws + 1572864;
    float* Av  = ws + 2097152;
    float* Bv  = ws + 2099200;
    float* out = (float*)d_out;

    k_transpose<<<dim3(256, 2), dim3(256), 0, stream>>>(Wl, Wr, WtL, WtR);
    k_proj<<<dim3(256), dim3(512), 0, stream>>>(x, WtL, WtR, bl, br, att, XL, XRt, Av, Bv);
    k_pair_topk<<<dim3(256), dim3(512), 0, stream>>>(XL, XRt, Av, Bv, att, out);
}